// Round 6
// baseline (366.066 us; speedup 1.0000x reference)
//
#include <hip/hip_runtime.h>
#include <hip/hip_bf16.h>

#define FDIM 128
#define TMB 16   // nodes per block
#define NRBF 20
#define PI_OVER_CUT 0.6283185307179586f  // pi / 5.0

static __device__ __forceinline__ unsigned short bf16_bits(float x) {
    unsigned u = __float_as_uint(x);
    unsigned r = u + 0x7FFF + ((u >> 16) & 1);   // round-to-nearest-even
    return (unsigned short)(r >> 16);
}
static __device__ __forceinline__ float bf16_f(unsigned short b) {
    return __uint_as_float(((unsigned)b) << 16);
}

// Per-node fused kernel v3: 256 threads, thread = (mg = tid>>5 -> 2 m-rows,
// cg = tid&31 -> 4 c-cols). Per 4-k step: 2 broadcast ds_read_b128 (s-rows)
// + 4 coalesced dwordx4 weight loads + 32 FMAs -> LDS issue per MAC cut 4x
// vs v2 (which was LDS-pipe bound at ~37K cyc/block).
__global__ __launch_bounds__(256) void node_kernel(
    const float* __restrict__ node_s, const float* __restrict__ node_vec,
    const float* __restrict__ edge_dis,
    const float* __restrict__ W1, const float* __restrict__ b1,
    const float* __restrict__ W2, const float* __restrict__ b2,
    const float* __restrict__ Wf, const float* __restrict__ bf,
    float4* __restrict__ VMf, ushort4* __restrict__ VMh, int use_f32, int N)
{
    __shared__ float sh_s[TMB][FDIM];   // node_s tile; overwritten with h
    __shared__ float sh_rbf[TMB][NRBF];
    __shared__ float sh_ccut[TMB];

    const int tid = threadIdx.x;
    const int mg  = tid >> 5;          // 0..7 -> rows 2mg, 2mg+1
    const int cg  = tid & 31;          // 0..31 -> cols 4cg..4cg+3
    const int n0  = blockIdx.x * TMB;
    const int c0  = 4 * cg;

    // stage node_s tile (16x128 floats = 512 float4)
    {
        const float4* g4 = (const float4*)(node_s + (size_t)n0 * FDIM);
        float4* s4 = (float4*)&sh_s[0][0];
        #pragma unroll
        for (int i = tid; i < TMB * FDIM / 4; i += 256) s4[i] = g4[i];
    }
    // rbf: 16 nodes x 20 k = 320 entries -> strided fill
    for (int idx = tid; idx < TMB * NRBF; idx += 256) {
        int m = idx / NRBF, k = idx - m * NRBF;
        float dd = edge_dis[n0 + m];
        sh_rbf[m][k] = sinf((float)(k + 1) * PI_OVER_CUT * dd) / dd;
    }
    if (tid < TMB) {
        float dd = edge_dis[n0 + tid];
        sh_ccut[tid] = (dd <= 5.0f) ? 0.5f * (cosf(PI_OVER_CUT * dd) + 1.0f) : 0.0f;
    }
    __syncthreads();

    float acc0[4], acc1[4];

    // ---- GEMM1: h = silu(s @ W1 + b1), tile 2m x 4c per thread ----
    #pragma unroll
    for (int i = 0; i < 4; i++) { acc0[i] = 0.f; acc1[i] = 0.f; }
    for (int k = 0; k < FDIM; k += 4) {
        float4 sa = *(const float4*)&sh_s[2 * mg + 0][k];
        float4 sb = *(const float4*)&sh_s[2 * mg + 1][k];
        #pragma unroll
        for (int j = 0; j < 4; j++) {
            float4 w = *(const float4*)&W1[(size_t)(k + j) * FDIM + c0];
            float s0 = (j == 0) ? sa.x : (j == 1) ? sa.y : (j == 2) ? sa.z : sa.w;
            float s1 = (j == 0) ? sb.x : (j == 1) ? sb.y : (j == 2) ? sb.z : sb.w;
            acc0[0] = fmaf(s0, w.x, acc0[0]); acc0[1] = fmaf(s0, w.y, acc0[1]);
            acc0[2] = fmaf(s0, w.z, acc0[2]); acc0[3] = fmaf(s0, w.w, acc0[3]);
            acc1[0] = fmaf(s1, w.x, acc1[0]); acc1[1] = fmaf(s1, w.y, acc1[1]);
            acc1[2] = fmaf(s1, w.z, acc1[2]); acc1[3] = fmaf(s1, w.w, acc1[3]);
        }
    }
    __syncthreads();   // all reads of sh_s done before overwrite
    {
        float4 bb = *(const float4*)&b1[c0];
        float4 h0, h1;
        float x;
        x = acc0[0] + bb.x; h0.x = x / (1.f + expf(-x));
        x = acc0[1] + bb.y; h0.y = x / (1.f + expf(-x));
        x = acc0[2] + bb.z; h0.z = x / (1.f + expf(-x));
        x = acc0[3] + bb.w; h0.w = x / (1.f + expf(-x));
        x = acc1[0] + bb.x; h1.x = x / (1.f + expf(-x));
        x = acc1[1] + bb.y; h1.y = x / (1.f + expf(-x));
        x = acc1[2] + bb.z; h1.z = x / (1.f + expf(-x));
        x = acc1[3] + bb.w; h1.w = x / (1.f + expf(-x));
        *(float4*)&sh_s[2 * mg + 0][c0] = h0;
        *(float4*)&sh_s[2 * mg + 1][c0] = h1;
    }
    __syncthreads();

    // ---- GEMM2 pass A: W2 cols [0,128) -> vector gate a ----
    #pragma unroll
    for (int i = 0; i < 4; i++) { acc0[i] = 0.f; acc1[i] = 0.f; }
    for (int k = 0; k < FDIM; k += 4) {
        float4 sa = *(const float4*)&sh_s[2 * mg + 0][k];
        float4 sb = *(const float4*)&sh_s[2 * mg + 1][k];
        #pragma unroll
        for (int j = 0; j < 4; j++) {
            float4 w = *(const float4*)&W2[(size_t)(k + j) * 384 + c0];
            float s0 = (j == 0) ? sa.x : (j == 1) ? sa.y : (j == 2) ? sa.z : sa.w;
            float s1 = (j == 0) ? sb.x : (j == 1) ? sb.y : (j == 2) ? sb.z : sb.w;
            acc0[0] = fmaf(s0, w.x, acc0[0]); acc0[1] = fmaf(s0, w.y, acc0[1]);
            acc0[2] = fmaf(s0, w.z, acc0[2]); acc0[3] = fmaf(s0, w.w, acc0[3]);
            acc1[0] = fmaf(s1, w.x, acc1[0]); acc1[1] = fmaf(s1, w.y, acc1[1]);
            acc1[2] = fmaf(s1, w.z, acc1[2]); acc1[3] = fmaf(s1, w.w, acc1[3]);
        }
    }
    float gA0[4], gA1[4];
    {
        float f0[4], f1[4];
        float4 bft = *(const float4*)&bf[c0];
        f0[0] = f1[0] = bft.x; f0[1] = f1[1] = bft.y;
        f0[2] = f1[2] = bft.z; f0[3] = f1[3] = bft.w;
        #pragma unroll
        for (int k = 0; k < NRBF; k++) {
            float4 w = *(const float4*)&Wf[(size_t)k * 384 + c0];
            float r0 = sh_rbf[2 * mg + 0][k];
            float r1 = sh_rbf[2 * mg + 1][k];
            f0[0] = fmaf(r0, w.x, f0[0]); f0[1] = fmaf(r0, w.y, f0[1]);
            f0[2] = fmaf(r0, w.z, f0[2]); f0[3] = fmaf(r0, w.w, f0[3]);
            f1[0] = fmaf(r1, w.x, f1[0]); f1[1] = fmaf(r1, w.y, f1[1]);
            f1[2] = fmaf(r1, w.z, f1[2]); f1[3] = fmaf(r1, w.w, f1[3]);
        }
        float cc0 = sh_ccut[2 * mg + 0];
        float cc1 = sh_ccut[2 * mg + 1];
        float4 b2t = *(const float4*)&b2[c0];
        gA0[0] = f0[0] * cc0 * (acc0[0] + b2t.x);
        gA0[1] = f0[1] * cc0 * (acc0[1] + b2t.y);
        gA0[2] = f0[2] * cc0 * (acc0[2] + b2t.z);
        gA0[3] = f0[3] * cc0 * (acc0[3] + b2t.w);
        gA1[0] = f1[0] * cc1 * (acc1[0] + b2t.x);
        gA1[1] = f1[1] * cc1 * (acc1[1] + b2t.y);
        gA1[2] = f1[2] * cc1 * (acc1[2] + b2t.z);
        gA1[3] = f1[3] * cc1 * (acc1[3] + b2t.w);
    }

    // ---- GEMM2 pass B: W2 cols [256,384) -> scalar message mm ----
    #pragma unroll
    for (int i = 0; i < 4; i++) { acc0[i] = 0.f; acc1[i] = 0.f; }
    for (int k = 0; k < FDIM; k += 4) {
        float4 sa = *(const float4*)&sh_s[2 * mg + 0][k];
        float4 sb = *(const float4*)&sh_s[2 * mg + 1][k];
        #pragma unroll
        for (int j = 0; j < 4; j++) {
            float4 w = *(const float4*)&W2[(size_t)(k + j) * 384 + 256 + c0];
            float s0 = (j == 0) ? sa.x : (j == 1) ? sa.y : (j == 2) ? sa.z : sa.w;
            float s1 = (j == 0) ? sb.x : (j == 1) ? sb.y : (j == 2) ? sb.z : sb.w;
            acc0[0] = fmaf(s0, w.x, acc0[0]); acc0[1] = fmaf(s0, w.y, acc0[1]);
            acc0[2] = fmaf(s0, w.z, acc0[2]); acc0[3] = fmaf(s0, w.w, acc0[3]);
            acc1[0] = fmaf(s1, w.x, acc1[0]); acc1[1] = fmaf(s1, w.y, acc1[1]);
            acc1[2] = fmaf(s1, w.z, acc1[2]); acc1[3] = fmaf(s1, w.w, acc1[3]);
        }
    }
    float mm0[4], mm1[4];
    {
        float f0[4], f1[4];
        float4 bft = *(const float4*)&bf[256 + c0];
        f0[0] = f1[0] = bft.x; f0[1] = f1[1] = bft.y;
        f0[2] = f1[2] = bft.z; f0[3] = f1[3] = bft.w;
        #pragma unroll
        for (int k = 0; k < NRBF; k++) {
            float4 w = *(const float4*)&Wf[(size_t)k * 384 + 256 + c0];
            float r0 = sh_rbf[2 * mg + 0][k];
            float r1 = sh_rbf[2 * mg + 1][k];
            f0[0] = fmaf(r0, w.x, f0[0]); f0[1] = fmaf(r0, w.y, f0[1]);
            f0[2] = fmaf(r0, w.z, f0[2]); f0[3] = fmaf(r0, w.w, f0[3]);
            f1[0] = fmaf(r1, w.x, f1[0]); f1[1] = fmaf(r1, w.y, f1[1]);
            f1[2] = fmaf(r1, w.z, f1[2]); f1[3] = fmaf(r1, w.w, f1[3]);
        }
        float cc0 = sh_ccut[2 * mg + 0];
        float cc1 = sh_ccut[2 * mg + 1];
        float4 b2t = *(const float4*)&b2[256 + c0];
        mm0[0] = f0[0] * cc0 * (acc0[0] + b2t.x);
        mm0[1] = f0[1] * cc0 * (acc0[1] + b2t.y);
        mm0[2] = f0[2] * cc0 * (acc0[2] + b2t.z);
        mm0[3] = f0[3] * cc0 * (acc0[3] + b2t.w);
        mm1[0] = f1[0] * cc1 * (acc1[0] + b2t.x);
        mm1[1] = f1[1] * cc1 * (acc1[1] + b2t.y);
        mm1[2] = f1[2] * cc1 * (acc1[2] + b2t.z);
        mm1[3] = f1[3] * cc1 * (acc1[3] + b2t.w);
    }

    // ---- epilogue: VM[n][c] = {a*v0, a*v1, a*v2, m} ----
    #pragma unroll
    for (int mi = 0; mi < 2; mi++) {
        int n = n0 + 2 * mg + mi;
        const float* vp = node_vec + (size_t)n * 384 + 3 * c0;  // 12 floats: 4 ch x xyz
        float4 v0 = *(const float4*)(vp + 0);
        float4 v1 = *(const float4*)(vp + 4);
        float4 v2 = *(const float4*)(vp + 8);
        float vv[12] = {v0.x, v0.y, v0.z, v0.w, v1.x, v1.y, v1.z, v1.w,
                        v2.x, v2.y, v2.z, v2.w};
        const float* ga = mi ? gA1 : gA0;
        const float* mv = mi ? mm1 : mm0;
        #pragma unroll
        for (int ci = 0; ci < 4; ci++) {
            float a = ga[ci];
            float x = a * vv[3 * ci + 0];
            float y = a * vv[3 * ci + 1];
            float z = a * vv[3 * ci + 2];
            size_t idx = (size_t)n * FDIM + c0 + ci;
            if (use_f32) {
                VMf[idx] = make_float4(x, y, z, mv[ci]);
            } else {
                ushort4 r;
                r.x = bf16_bits(x); r.y = bf16_bits(y);
                r.z = bf16_bits(z); r.w = bf16_bits(mv[ci]);
                VMh[idx] = r;
            }
        }
    }
}

// ---------------- CSR build ------------------------------------------------
__global__ __launch_bounds__(256) void hist_kernel(
    const int* __restrict__ edge, int* __restrict__ counts, int E)
{
    int i = blockIdx.x * 256 + threadIdx.x;
    if (i < E) atomicAdd(&counts[edge[2 * i]], 1);
}

__global__ __launch_bounds__(1024) void scan_kernel(
    const int* __restrict__ counts, int* __restrict__ offsets,
    int* __restrict__ cursor, int N)
{
    __shared__ int sh[1024];
    const int t = threadIdx.x;
    const int chunk = (N + 1023) / 1024;
    const int beg = t * chunk, end = min(beg + chunk, N);

    int local = 0;
    for (int i = beg; i < end; i++) local += counts[i];
    sh[t] = local;
    __syncthreads();
    for (int off = 1; off < 1024; off <<= 1) {
        int v = (t >= off) ? sh[t - off] : 0;
        __syncthreads();
        sh[t] += v;
        __syncthreads();
    }
    int run = sh[t] - local;  // exclusive prefix of this chunk
    for (int i = beg; i < end; i++) {
        offsets[i] = run;
        cursor[i] = run;
        run += counts[i];
    }
    if (t == 1023) offsets[N] = sh[1023];
}

__global__ __launch_bounds__(256) void scatter_kernel(
    const int* __restrict__ edge, int* __restrict__ cursor,
    int* __restrict__ src_sorted, int E)
{
    int i = blockIdx.x * 256 + threadIdx.x;
    if (i >= E) return;
    int d = edge[2 * i];
    int s = edge[2 * i + 1];
    int pos = atomicAdd(&cursor[d], 1);
    src_sorted[pos] = s;
}

// ------- gather: one dst per 128 threads, single dwordx4 stream ------------
__global__ __launch_bounds__(256) void gather_f32(
    const int* __restrict__ offsets, const int* __restrict__ src_sorted,
    const float4* __restrict__ VM, const float* __restrict__ node_vec,
    const float* __restrict__ node_s,
    float* __restrict__ out_vec, float* __restrict__ out_s, int N)
{
    int d = blockIdx.x * 2 + (threadIdx.x >> 7);
    int c = threadIdx.x & 127;
    if (d >= N) return;

    int beg = offsets[d];
    int end = offsets[d + 1];

    float a0 = 0.f, a1 = 0.f, a2 = 0.f, as = 0.f;
    int j = beg;
    for (; j + 3 < end; j += 4) {
        int s0 = src_sorted[j], s1 = src_sorted[j + 1];
        int s2 = src_sorted[j + 2], s3 = src_sorted[j + 3];
        float4 r0 = VM[(size_t)s0 * FDIM + c];
        float4 r1 = VM[(size_t)s1 * FDIM + c];
        float4 r2 = VM[(size_t)s2 * FDIM + c];
        float4 r3 = VM[(size_t)s3 * FDIM + c];
        a0 += (r0.x + r1.x) + (r2.x + r3.x);
        a1 += (r0.y + r1.y) + (r2.y + r3.y);
        a2 += (r0.z + r1.z) + (r2.z + r3.z);
        as += (r0.w + r1.w) + (r2.w + r3.w);
    }
    for (; j < end; j++) {
        float4 r = VM[(size_t)src_sorted[j] * FDIM + c];
        a0 += r.x; a1 += r.y; a2 += r.z; as += r.w;
    }

    out_s[(size_t)d * FDIM + c] = node_s[(size_t)d * FDIM + c] + as;
    const float* ip = node_vec + (size_t)d * 384 + 3 * c;
    float* op = out_vec + (size_t)d * 384 + 3 * c;
    op[0] = ip[0] + a0;
    op[1] = ip[1] + a1;
    op[2] = ip[2] + a2;
}

__global__ __launch_bounds__(256) void gather_bf16(
    const int* __restrict__ offsets, const int* __restrict__ src_sorted,
    const ushort4* __restrict__ VM, const float* __restrict__ node_vec,
    const float* __restrict__ node_s,
    float* __restrict__ out_vec, float* __restrict__ out_s, int N)
{
    int d = blockIdx.x * 2 + (threadIdx.x >> 7);
    int c = threadIdx.x & 127;
    if (d >= N) return;

    int beg = offsets[d];
    int end = offsets[d + 1];

    float a0 = 0.f, a1 = 0.f, a2 = 0.f, as = 0.f;
    int j = beg;
    for (; j + 1 < end; j += 2) {
        ushort4 r0 = VM[(size_t)src_sorted[j] * FDIM + c];
        ushort4 r1 = VM[(size_t)src_sorted[j + 1] * FDIM + c];
        a0 += bf16_f(r0.x) + bf16_f(r1.x);
        a1 += bf16_f(r0.y) + bf16_f(r1.y);
        a2 += bf16_f(r0.z) + bf16_f(r1.z);
        as += bf16_f(r0.w) + bf16_f(r1.w);
    }
    for (; j < end; j++) {
        ushort4 r = VM[(size_t)src_sorted[j] * FDIM + c];
        a0 += bf16_f(r.x); a1 += bf16_f(r.y); a2 += bf16_f(r.z); as += bf16_f(r.w);
    }

    out_s[(size_t)d * FDIM + c] = node_s[(size_t)d * FDIM + c] + as;
    const float* ip = node_vec + (size_t)d * 384 + 3 * c;
    float* op = out_vec + (size_t)d * 384 + 3 * c;
    op[0] = ip[0] + a0;
    op[1] = ip[1] + a1;
    op[2] = ip[2] + a2;
}

extern "C" void kernel_launch(void* const* d_in, const int* in_sizes, int n_in,
                              void* d_out, int out_size, void* d_ws, size_t ws_size,
                              hipStream_t stream) {
    const float* node_s   = (const float*)d_in[0];
    const float* node_vec = (const float*)d_in[1];
    const int*   edge     = (const int*)d_in[2];
    const float* edge_dis = (const float*)d_in[4];
    const float* W1 = (const float*)d_in[5];
    const float* b1 = (const float*)d_in[6];
    const float* W2 = (const float*)d_in[7];
    const float* b2 = (const float*)d_in[8];
    const float* Wf = (const float*)d_in[9];
    const float* bf = (const float*)d_in[10];

    const int N = in_sizes[0] / FDIM;
    const int E = in_sizes[2] / 2;

    float* out_vec = (float*)d_out;              // N*128*3
    float* out_s   = out_vec + (size_t)N * 384;  // N*128

    // workspace: ints first, then VM (16B-aligned)
    int* counts     = (int*)d_ws;          // N
    int* offsets    = counts + N;          // N+1
    int* cursor     = offsets + N + 1;     // N
    int* src_sorted = cursor + N;          // E
    size_t int_bytes = (((size_t)(3 * N + 1 + E) * 4) + 15) & ~(size_t)15;
    void* vm_base = (char*)d_ws + int_bytes;

    size_t need_f32 = int_bytes + (size_t)N * FDIM * sizeof(float4);
    int use_f32 = (ws_size >= need_f32) ? 1 : 0;
    float4*  VMf = (float4*)vm_base;
    ushort4* VMh = (ushort4*)vm_base;

    hipMemsetAsync(counts, 0, (size_t)N * sizeof(int), stream);

    node_kernel<<<(N + TMB - 1) / TMB, 256, 0, stream>>>(
        node_s, node_vec, edge_dis, W1, b1, W2, b2, Wf, bf, VMf, VMh, use_f32, N);

    hist_kernel<<<(E + 255) / 256, 256, 0, stream>>>(edge, counts, E);
    scan_kernel<<<1, 1024, 0, stream>>>(counts, offsets, cursor, N);
    scatter_kernel<<<(E + 255) / 256, 256, 0, stream>>>(edge, cursor, src_sorted, E);

    if (use_f32) {
        gather_f32<<<(N + 1) / 2, 256, 0, stream>>>(
            offsets, src_sorted, VMf, node_vec, node_s, out_vec, out_s, N);
    } else {
        gather_bf16<<<(N + 1) / 2, 256, 0, stream>>>(
            offsets, src_sorted, VMh, node_vec, node_s, out_vec, out_s, N);
    }
}

// Round 7
// 305.732 us; speedup vs baseline: 1.1973x; 1.1973x over previous
//
#include <hip/hip_runtime.h>
#include <hip/hip_bf16.h>

#define FDIM 128
#define NRBF 20
#define PI_OVER_CUT 0.6283185307179586f  // pi / 5.0

typedef short bf8_t __attribute__((ext_vector_type(8)));   // 8 bf16 (4 VGPRs)
typedef float f4_t  __attribute__((ext_vector_type(4)));   // 4 fp32 acc

static __device__ __forceinline__ unsigned short bf16_bits(float x) {
    unsigned u = __float_as_uint(x);
    unsigned r = u + 0x7FFF + ((u >> 16) & 1);   // round-to-nearest-even
    return (unsigned short)(r >> 16);
}
static __device__ __forceinline__ float bf16_f(unsigned short b) {
    return __uint_as_float(((unsigned)b) << 16);
}

// ---- weight prep: W1T[n][k] = bf16(W1[k][n]); W2T[n][k] = bf16(W2[k][colmap(n)])
// colmap(n) = n<128 ? n : n+128  (gate cols 0..127, message cols 256..383)
__global__ __launch_bounds__(256) void convert_w(
    const float* __restrict__ W1, const float* __restrict__ W2,
    unsigned short* __restrict__ W1T, unsigned short* __restrict__ W2T)
{
    int i = blockIdx.x * 256 + threadIdx.x;
    if (i < 128 * 128) {
        int n = i >> 7, k = i & 127;
        W1T[n * 128 + k] = bf16_bits(W1[k * 128 + n]);
    } else if (i < 128 * 128 + 256 * 128) {
        int j = i - 128 * 128;
        int n = j >> 7, k = j & 127;
        int col = (n < 128) ? n : n + 128;
        W2T[n * 128 + k] = bf16_bits(W2[k * 384 + col]);
    }
}

// ---- GEMM1: H_bf = bf16(silu(S @ W1 + b1)), M=N nodes, N=128, K=128 -------
// block = 4 waves; wave = 16-row strip; 8 n-tiles x 4 k-steps of 16x16x32 MFMA.
__global__ __launch_bounds__(256) void gemm1_kernel(
    const float* __restrict__ S, const unsigned short* __restrict__ W1T,
    const float* __restrict__ b1, unsigned short* __restrict__ H, int N)
{
    const int lane = threadIdx.x & 63;
    const int wave = threadIdx.x >> 6;
    const int l15  = lane & 15;
    const int quad = lane >> 4;                  // 0..3
    const int m0   = blockIdx.x * 64 + wave * 16;

    // A-fragments: A[m=l15][k=quad*8+j], converted fp32->bf16 on the fly
    bf8_t a[4];
    {
        int row = min(m0 + l15, N - 1);
        const float* sp = S + (size_t)row * FDIM + quad * 8;
        #pragma unroll
        for (int kk = 0; kk < 4; kk++) {
            float4 x0 = *(const float4*)(sp + kk * 32 + 0);
            float4 x1 = *(const float4*)(sp + kk * 32 + 4);
            bf8_t t;
            t[0] = (short)bf16_bits(x0.x); t[1] = (short)bf16_bits(x0.y);
            t[2] = (short)bf16_bits(x0.z); t[3] = (short)bf16_bits(x0.w);
            t[4] = (short)bf16_bits(x1.x); t[5] = (short)bf16_bits(x1.y);
            t[6] = (short)bf16_bits(x1.z); t[7] = (short)bf16_bits(x1.w);
            a[kk] = t;
        }
    }

    #pragma unroll
    for (int nt = 0; nt < 8; nt++) {
        int col = nt * 16 + l15;
        const unsigned short* wp = W1T + (size_t)col * FDIM + quad * 8;
        f4_t acc = {0.f, 0.f, 0.f, 0.f};
        #pragma unroll
        for (int kk = 0; kk < 4; kk++) {
            bf8_t b = *(const bf8_t*)(wp + kk * 32);
            acc = __builtin_amdgcn_mfma_f32_16x16x32_bf16(a[kk], b, acc, 0, 0, 0);
        }
        float bcol = b1[col];
        #pragma unroll
        for (int r = 0; r < 4; r++) {
            int row = m0 + quad * 4 + r;          // C/D: row = quad*4 + reg
            if (row < N) {
                float x = acc[r] + bcol;
                x = x / (1.f + expf(-x));
                H[(size_t)row * FDIM + col] = bf16_bits(x);
            }
        }
    }
}

// ---- GEMM2: SO_bf = bf16(H @ W2p + b2p), N=256 packed cols ----------------
__global__ __launch_bounds__(256) void gemm2_kernel(
    const unsigned short* __restrict__ H, const unsigned short* __restrict__ W2T,
    const float* __restrict__ b2, unsigned short* __restrict__ SO, int N)
{
    const int lane = threadIdx.x & 63;
    const int wave = threadIdx.x >> 6;
    const int l15  = lane & 15;
    const int quad = lane >> 4;
    const int m0   = blockIdx.x * 64 + wave * 16;

    bf8_t a[4];
    {
        int row = min(m0 + l15, N - 1);
        const unsigned short* hp = H + (size_t)row * FDIM + quad * 8;
        #pragma unroll
        for (int kk = 0; kk < 4; kk++) a[kk] = *(const bf8_t*)(hp + kk * 32);
    }

    #pragma unroll
    for (int nt = 0; nt < 16; nt++) {
        int col = nt * 16 + l15;                  // packed col 0..255
        const unsigned short* wp = W2T + (size_t)col * FDIM + quad * 8;
        f4_t acc = {0.f, 0.f, 0.f, 0.f};
        #pragma unroll
        for (int kk = 0; kk < 4; kk++) {
            bf8_t b = *(const bf8_t*)(wp + kk * 32);
            acc = __builtin_amdgcn_mfma_f32_16x16x32_bf16(a[kk], b, acc, 0, 0, 0);
        }
        float bcol = b2[(col < 128) ? col : col + 128];
        #pragma unroll
        for (int r = 0; r < 4; r++) {
            int row = m0 + quad * 4 + r;
            if (row < N) SO[(size_t)row * 256 + col] = bf16_bits(acc[r] + bcol);
        }
    }
}

// ---- per-node filter epilogue: VM[n][c] = bf16{a*v0, a*v1, a*v2, m} -------
__global__ __launch_bounds__(256) void vm_kernel(
    const unsigned short* __restrict__ SO, const float* __restrict__ node_vec,
    const float* __restrict__ edge_dis,
    const float* __restrict__ Wf, const float* __restrict__ bfv,
    ushort4* __restrict__ VMh, int N)
{
    __shared__ float sh_rbf[16][NRBF];
    __shared__ float sh_ccut[16];

    const int tid = threadIdx.x;
    const int h   = tid >> 7;      // 0/1
    const int c   = tid & 127;
    const int n0  = blockIdx.x * 16;

    for (int idx = tid; idx < 16 * NRBF; idx += 256) {
        int m = idx / NRBF, k = idx - m * NRBF;
        float dd = edge_dis[n0 + m];
        sh_rbf[m][k] = sinf((float)(k + 1) * PI_OVER_CUT * dd) / dd;
    }
    if (tid < 16) {
        float dd = edge_dis[n0 + tid];
        sh_ccut[tid] = (dd <= 5.0f) ? 0.5f * (cosf(PI_OVER_CUT * dd) + 1.0f) : 0.0f;
    }
    __syncthreads();

    float bg = bfv[c], bm = bfv[256 + c];
    for (int mi = h; mi < 16; mi += 2) {
        int n = n0 + mi;
        if (n >= N) break;
        float sog = bf16_f(SO[(size_t)n * 256 + c]);
        float som = bf16_f(SO[(size_t)n * 256 + 128 + c]);
        float fg = bg, fm = bm;
        #pragma unroll
        for (int k = 0; k < NRBF; k++) {
            float r = sh_rbf[mi][k];
            fg = fmaf(r, Wf[k * 384 + c], fg);
            fm = fmaf(r, Wf[k * 384 + 256 + c], fm);
        }
        float cc = sh_ccut[mi];
        float a  = fg * cc * sog;
        float m_ = fm * cc * som;
        const float* vp = node_vec + (size_t)n * 384 + 3 * c;
        ushort4 rec;
        rec.x = bf16_bits(a * vp[0]);
        rec.y = bf16_bits(a * vp[1]);
        rec.z = bf16_bits(a * vp[2]);
        rec.w = bf16_bits(m_);
        VMh[(size_t)n * FDIM + c] = rec;
    }
}

// ---------------- CSR build ------------------------------------------------
__global__ __launch_bounds__(256) void hist_kernel(
    const int* __restrict__ edge, int* __restrict__ counts, int E)
{
    int i = blockIdx.x * 256 + threadIdx.x;
    if (i < E) atomicAdd(&counts[edge[2 * i]], 1);
}

__global__ __launch_bounds__(1024) void scan_kernel(
    const int* __restrict__ counts, int* __restrict__ offsets,
    int* __restrict__ cursor, int N)
{
    __shared__ int sh[1024];
    const int t = threadIdx.x;
    const int chunk = (N + 1023) / 1024;
    const int beg = t * chunk, end = min(beg + chunk, N);

    int local = 0;
    for (int i = beg; i < end; i++) local += counts[i];
    sh[t] = local;
    __syncthreads();
    for (int off = 1; off < 1024; off <<= 1) {
        int v = (t >= off) ? sh[t - off] : 0;
        __syncthreads();
        sh[t] += v;
        __syncthreads();
    }
    int run = sh[t] - local;  // exclusive prefix of this chunk
    for (int i = beg; i < end; i++) {
        offsets[i] = run;
        cursor[i] = run;
        run += counts[i];
    }
    if (t == 1023) offsets[N] = sh[1023];
}

__global__ __launch_bounds__(256) void scatter_kernel(
    const int* __restrict__ edge, int* __restrict__ cursor,
    int* __restrict__ src_sorted, int E)
{
    int i = blockIdx.x * 256 + threadIdx.x;
    if (i >= E) return;
    int d = edge[2 * i];
    int s = edge[2 * i + 1];
    int pos = atomicAdd(&cursor[d], 1);
    src_sorted[pos] = s;
}

// ------- gather: one dst per 128 threads, 8B bf16 records, 4x unroll -------
__global__ __launch_bounds__(256) void gather_bf16(
    const int* __restrict__ offsets, const int* __restrict__ src_sorted,
    const ushort4* __restrict__ VM, const float* __restrict__ node_vec,
    const float* __restrict__ node_s,
    float* __restrict__ out_vec, float* __restrict__ out_s, int N)
{
    int d = blockIdx.x * 2 + (threadIdx.x >> 7);
    int c = threadIdx.x & 127;
    if (d >= N) return;

    int beg = offsets[d];
    int end = offsets[d + 1];

    float a0 = 0.f, a1 = 0.f, a2 = 0.f, as = 0.f;
    int j = beg;
    for (; j + 3 < end; j += 4) {
        ushort4 r0 = VM[(size_t)src_sorted[j]     * FDIM + c];
        ushort4 r1 = VM[(size_t)src_sorted[j + 1] * FDIM + c];
        ushort4 r2 = VM[(size_t)src_sorted[j + 2] * FDIM + c];
        ushort4 r3 = VM[(size_t)src_sorted[j + 3] * FDIM + c];
        a0 += (bf16_f(r0.x) + bf16_f(r1.x)) + (bf16_f(r2.x) + bf16_f(r3.x));
        a1 += (bf16_f(r0.y) + bf16_f(r1.y)) + (bf16_f(r2.y) + bf16_f(r3.y));
        a2 += (bf16_f(r0.z) + bf16_f(r1.z)) + (bf16_f(r2.z) + bf16_f(r3.z));
        as += (bf16_f(r0.w) + bf16_f(r1.w)) + (bf16_f(r2.w) + bf16_f(r3.w));
    }
    for (; j < end; j++) {
        ushort4 r = VM[(size_t)src_sorted[j] * FDIM + c];
        a0 += bf16_f(r.x); a1 += bf16_f(r.y); a2 += bf16_f(r.z); as += bf16_f(r.w);
    }

    out_s[(size_t)d * FDIM + c] = node_s[(size_t)d * FDIM + c] + as;
    const float* ip = node_vec + (size_t)d * 384 + 3 * c;
    float* op = out_vec + (size_t)d * 384 + 3 * c;
    op[0] = ip[0] + a0;
    op[1] = ip[1] + a1;
    op[2] = ip[2] + a2;
}

extern "C" void kernel_launch(void* const* d_in, const int* in_sizes, int n_in,
                              void* d_out, int out_size, void* d_ws, size_t ws_size,
                              hipStream_t stream) {
    const float* node_s   = (const float*)d_in[0];
    const float* node_vec = (const float*)d_in[1];
    const int*   edge     = (const int*)d_in[2];
    const float* edge_dis = (const float*)d_in[4];
    const float* W1 = (const float*)d_in[5];
    const float* b1 = (const float*)d_in[6];
    const float* W2 = (const float*)d_in[7];
    const float* b2 = (const float*)d_in[8];
    const float* Wf = (const float*)d_in[9];
    const float* bf = (const float*)d_in[10];

    const int N = in_sizes[0] / FDIM;
    const int E = in_sizes[2] / 2;

    float* out_vec = (float*)d_out;              // N*128*3
    float* out_s   = out_vec + (size_t)N * 384;  // N*128

    // workspace layout (≈37.5 MB total)
    int* counts     = (int*)d_ws;          // N
    int* offsets    = counts + N;          // N+1
    int* cursor     = offsets + N + 1;     // N
    int* src_sorted = cursor + N;          // E
    size_t int_bytes = (((size_t)(3 * N + 1 + E) * 4) + 15) & ~(size_t)15;
    unsigned short* W1T = (unsigned short*)((char*)d_ws + int_bytes);  // 128*128
    unsigned short* W2T = W1T + 128 * 128;                             // 256*128
    unsigned short* Hbf = W2T + 256 * 128;                             // N*128
    unsigned short* SO  = Hbf + (size_t)N * FDIM;                      // N*256
    ushort4*        VMh = (ushort4*)(SO + (size_t)N * 256);            // N*128

    hipMemsetAsync(counts, 0, (size_t)N * sizeof(int), stream);

    convert_w<<<(128 * 128 + 256 * 128 + 255) / 256, 256, 0, stream>>>(W1, W2, W1T, W2T);

    const int mblocks = (N + 63) / 64;
    gemm1_kernel<<<mblocks, 256, 0, stream>>>(node_s, W1T, b1, Hbf, N);
    gemm2_kernel<<<mblocks, 256, 0, stream>>>(Hbf, W2T, b2, SO, N);
    vm_kernel<<<(N + 15) / 16, 256, 0, stream>>>(SO, node_vec, edge_dis, Wf, bf, VMh, N);

    hist_kernel<<<(E + 255) / 256, 256, 0, stream>>>(edge, counts, E);
    scan_kernel<<<1, 1024, 0, stream>>>(counts, offsets, cursor, N);
    scatter_kernel<<<(E + 255) / 256, 256, 0, stream>>>(edge, cursor, src_sorted, E);

    gather_bf16<<<(N + 1) / 2, 256, 0, stream>>>(
        offsets, src_sorted, VMh, node_vec, node_s, out_vec, out_s, N);
}

// Round 8
// 262.180 us; speedup vs baseline: 1.3962x; 1.1661x over previous
//
#include <hip/hip_runtime.h>
#include <hip/hip_bf16.h>

#define FDIM 128
#define NRBF 20
#define PI_OVER_CUT 0.6283185307179586f  // pi / 5.0

typedef short bf8_t __attribute__((ext_vector_type(8)));   // 8 bf16 (4 VGPRs)
typedef float f4_t  __attribute__((ext_vector_type(4)));   // 4 fp32 acc

static __device__ __forceinline__ unsigned short bf16_bits(float x) {
    unsigned u = __float_as_uint(x);
    unsigned r = u + 0x7FFF + ((u >> 16) & 1);   // round-to-nearest-even
    return (unsigned short)(r >> 16);
}
static __device__ __forceinline__ float bf16_f(unsigned short b) {
    return __uint_as_float(((unsigned)b) << 16);
}

// ---- weight prep (bf16, transposed to [col][k]):
//   W1T[n][k]  = W1[k][n]                (128 x 128)
//   W2T[n][k]  = W2[k][colmap(n)]        (256 x 128), colmap(n)= n<128 ? n : n+128
//   WfT[n][k]  = k<20 ? Wf[k][colmap(n)] : 0   (256 x 32, K padded 20->32)
__global__ __launch_bounds__(256) void convert_w(
    const float* __restrict__ W1, const float* __restrict__ W2,
    const float* __restrict__ Wf,
    unsigned short* __restrict__ W1T, unsigned short* __restrict__ W2T,
    unsigned short* __restrict__ WfT)
{
    int i = blockIdx.x * 256 + threadIdx.x;
    if (i < 128 * 128) {
        int n = i >> 7, k = i & 127;
        W1T[n * 128 + k] = bf16_bits(W1[k * 128 + n]);
    } else if (i < 128 * 128 + 256 * 128) {
        int j = i - 128 * 128;
        int n = j >> 7, k = j & 127;
        int col = (n < 128) ? n : n + 128;
        W2T[n * 128 + k] = bf16_bits(W2[k * 384 + col]);
    } else if (i < 128 * 128 + 256 * 128 + 256 * 32) {
        int j = i - (128 * 128 + 256 * 128);
        int n = j >> 5, k = j & 31;
        int col = (n < 128) ? n : n + 128;
        WfT[n * 32 + k] = (k < NRBF) ? bf16_bits(Wf[k * 384 + col]) : (unsigned short)0;
    }
}

// ---- fully fused per-node kernel ------------------------------------------
// Block = 256 thr = 4 waves, 32 rows. wave = (strip = (w&1)*16, colhalf = w>>1).
// Phase 0: stage node_s->bf16 LDS, rbf->bf16 LDS (K padded to 32), ccut.
// Phase 1: H = silu(S@W1+b1) via MFMA -> LDS (each wave: its strip x 64 cols).
// Phase 2: per 16-col tile: SO gate/msg (4 MFMA each) + filt gate/msg (1 MFMA
//          each, K=32) -> epilogue writes VM[n][c] = bf16{a*v0,a*v1,a*v2,m}.
// LDS rows padded +8 ushorts (16B) so row strides (272B / 80B) stay 16B-aligned
// while breaking power-of-2 bank aliasing.
__global__ __launch_bounds__(256) void node_fused(
    const float* __restrict__ S, const float* __restrict__ node_vec,
    const float* __restrict__ edge_dis,
    const unsigned short* __restrict__ W1T, const float* __restrict__ b1,
    const unsigned short* __restrict__ W2T, const float* __restrict__ b2,
    const unsigned short* __restrict__ WfT, const float* __restrict__ bfv,
    ushort4* __restrict__ VM, int N)
{
    __shared__ __align__(16) unsigned short sh_s[32][136];
    __shared__ __align__(16) unsigned short sh_h[32][136];
    __shared__ __align__(16) unsigned short sh_rbf[32][40];
    __shared__ float sh_ccut[32];

    const int tid   = threadIdx.x;
    const int lane  = tid & 63;
    const int wave  = tid >> 6;
    const int l15   = lane & 15;
    const int quad  = lane >> 4;
    const int strip = (wave & 1) * 16;
    const int ch    = wave >> 1;          // column half 0/1
    const int m0    = blockIdx.x * 32;

    // ---- phase 0: staging ----
    for (int t = tid; t < 32 * 32; t += 256) {          // node_s: 1024 float4
        int row = t >> 5, c4 = (t & 31) * 4;
        int n = m0 + row; if (n >= N) n = N - 1;
        float4 x = *(const float4*)(S + (size_t)n * FDIM + c4);
        ushort4 u;
        u.x = bf16_bits(x.x); u.y = bf16_bits(x.y);
        u.z = bf16_bits(x.z); u.w = bf16_bits(x.w);
        *(ushort4*)&sh_s[row][c4] = u;
    }
    for (int t = tid; t < 32 * 8; t += 256) {           // rbf: 32 rows x 8 k-quads
        int row = t >> 3, k0 = (t & 7) * 4;
        int n = m0 + row; if (n >= N) n = N - 1;
        float dd = edge_dis[n];
        float ph = PI_OVER_CUT * dd;
        float inv = 1.0f / dd;
        ushort4 u;
        u.x = (k0 + 0 < NRBF) ? bf16_bits(sinf((float)(k0 + 1) * ph) * inv) : 0;
        u.y = (k0 + 1 < NRBF) ? bf16_bits(sinf((float)(k0 + 2) * ph) * inv) : 0;
        u.z = (k0 + 2 < NRBF) ? bf16_bits(sinf((float)(k0 + 3) * ph) * inv) : 0;
        u.w = (k0 + 3 < NRBF) ? bf16_bits(sinf((float)(k0 + 4) * ph) * inv) : 0;
        *(ushort4*)&sh_rbf[row][k0] = u;
    }
    if (tid < 32) {
        int n = m0 + tid; if (n >= N) n = N - 1;
        float dd = edge_dis[n];
        sh_ccut[tid] = (dd <= 5.0f) ? 0.5f * (cosf(PI_OVER_CUT * dd) + 1.0f) : 0.0f;
    }
    __syncthreads();

    const int arow = strip + l15;

    // ---- phase 1: GEMM1 + silu -> sh_h ----
    {
        bf8_t a1[4];
        #pragma unroll
        for (int kk = 0; kk < 4; kk++)
            a1[kk] = *(const bf8_t*)&sh_s[arow][kk * 32 + quad * 8];

        #pragma unroll
        for (int i = 0; i < 4; i++) {
            int col = (ch * 4 + i) * 16 + l15;
            const unsigned short* wp = W1T + (size_t)col * FDIM + quad * 8;
            f4_t acc = {0.f, 0.f, 0.f, 0.f};
            #pragma unroll
            for (int kk = 0; kk < 4; kk++) {
                bf8_t b = *(const bf8_t*)(wp + kk * 32);
                acc = __builtin_amdgcn_mfma_f32_16x16x32_bf16(a1[kk], b, acc, 0, 0, 0);
            }
            float bb = b1[col];
            #pragma unroll
            for (int r = 0; r < 4; r++) {
                float x = acc[r] + bb;
                x = x / (1.f + expf(-x));
                sh_h[strip + quad * 4 + r][col] = bf16_bits(x);
            }
        }
    }
    __syncthreads();

    // ---- phase 2: GEMM2 (gate+msg) + filter GEMM + epilogue ----
    bf8_t a2[4], af;
    #pragma unroll
    for (int kk = 0; kk < 4; kk++)
        a2[kk] = *(const bf8_t*)&sh_h[arow][kk * 32 + quad * 8];
    af = *(const bf8_t*)&sh_rbf[arow][quad * 8];

    #pragma unroll
    for (int i = 0; i < 4; i++) {
        int pc = (ch * 4 + i) * 16 + l15;        // packed col 0..127
        const unsigned short* wg = W2T + (size_t)pc * FDIM + quad * 8;
        const unsigned short* wm = W2T + (size_t)(pc + 128) * FDIM + quad * 8;
        f4_t ag = {0.f, 0.f, 0.f, 0.f}, am = {0.f, 0.f, 0.f, 0.f};
        #pragma unroll
        for (int kk = 0; kk < 4; kk++) {
            bf8_t bg = *(const bf8_t*)(wg + kk * 32);
            bf8_t bm = *(const bf8_t*)(wm + kk * 32);
            ag = __builtin_amdgcn_mfma_f32_16x16x32_bf16(a2[kk], bg, ag, 0, 0, 0);
            am = __builtin_amdgcn_mfma_f32_16x16x32_bf16(a2[kk], bm, am, 0, 0, 0);
        }
        f4_t fg = {0.f, 0.f, 0.f, 0.f}, fm = {0.f, 0.f, 0.f, 0.f};
        {
            bf8_t bg = *(const bf8_t*)(WfT + (size_t)pc * 32 + quad * 8);
            bf8_t bm = *(const bf8_t*)(WfT + (size_t)(pc + 128) * 32 + quad * 8);
            fg = __builtin_amdgcn_mfma_f32_16x16x32_bf16(af, bg, fg, 0, 0, 0);
            fm = __builtin_amdgcn_mfma_f32_16x16x32_bf16(af, bm, fm, 0, 0, 0);
        }

        float b2g = b2[pc], b2m = b2[256 + pc];
        float bfg = bfv[pc], bfm = bfv[256 + pc];
        #pragma unroll
        for (int r = 0; r < 4; r++) {
            int lrow = strip + quad * 4 + r;
            int n = m0 + lrow;
            if (n < N) {
                float cc = sh_ccut[lrow];
                float a  = (fg[r] + bfg) * cc * (ag[r] + b2g);
                float mv = (fm[r] + bfm) * cc * (am[r] + b2m);
                const float* vp = node_vec + (size_t)n * 384 + 3 * pc;
                ushort4 rec;
                rec.x = bf16_bits(a * vp[0]);
                rec.y = bf16_bits(a * vp[1]);
                rec.z = bf16_bits(a * vp[2]);
                rec.w = bf16_bits(mv);
                VM[(size_t)n * FDIM + pc] = rec;
            }
        }
    }
}

// ---------------- CSR build ------------------------------------------------
__global__ __launch_bounds__(256) void hist_kernel(
    const int* __restrict__ edge, int* __restrict__ counts, int E)
{
    int i = blockIdx.x * 256 + threadIdx.x;
    if (i < E) atomicAdd(&counts[edge[2 * i]], 1);
}

__global__ __launch_bounds__(1024) void scan_kernel(
    const int* __restrict__ counts, int* __restrict__ offsets,
    int* __restrict__ cursor, int N)
{
    __shared__ int sh[1024];
    const int t = threadIdx.x;
    const int chunk = (N + 1023) / 1024;
    const int beg = t * chunk, end = min(beg + chunk, N);

    int local = 0;
    for (int i = beg; i < end; i++) local += counts[i];
    sh[t] = local;
    __syncthreads();
    for (int off = 1; off < 1024; off <<= 1) {
        int v = (t >= off) ? sh[t - off] : 0;
        __syncthreads();
        sh[t] += v;
        __syncthreads();
    }
    int run = sh[t] - local;  // exclusive prefix of this chunk
    for (int i = beg; i < end; i++) {
        offsets[i] = run;
        cursor[i] = run;
        run += counts[i];
    }
    if (t == 1023) offsets[N] = sh[1023];
}

__global__ __launch_bounds__(256) void scatter_kernel(
    const int* __restrict__ edge, int* __restrict__ cursor,
    int* __restrict__ src_sorted, int E)
{
    int i = blockIdx.x * 256 + threadIdx.x;
    if (i >= E) return;
    int d = edge[2 * i];
    int s = edge[2 * i + 1];
    int pos = atomicAdd(&cursor[d], 1);
    src_sorted[pos] = s;
}

// ------- gather: one dst per 128 threads, 8B bf16 records, 4x unroll -------
__global__ __launch_bounds__(256) void gather_bf16(
    const int* __restrict__ offsets, const int* __restrict__ src_sorted,
    const ushort4* __restrict__ VM, const float* __restrict__ node_vec,
    const float* __restrict__ node_s,
    float* __restrict__ out_vec, float* __restrict__ out_s, int N)
{
    int d = blockIdx.x * 2 + (threadIdx.x >> 7);
    int c = threadIdx.x & 127;
    if (d >= N) return;

    int beg = offsets[d];
    int end = offsets[d + 1];

    float a0 = 0.f, a1 = 0.f, a2 = 0.f, as = 0.f;
    int j = beg;
    for (; j + 3 < end; j += 4) {
        ushort4 r0 = VM[(size_t)src_sorted[j]     * FDIM + c];
        ushort4 r1 = VM[(size_t)src_sorted[j + 1] * FDIM + c];
        ushort4 r2 = VM[(size_t)src_sorted[j + 2] * FDIM + c];
        ushort4 r3 = VM[(size_t)src_sorted[j + 3] * FDIM + c];
        a0 += (bf16_f(r0.x) + bf16_f(r1.x)) + (bf16_f(r2.x) + bf16_f(r3.x));
        a1 += (bf16_f(r0.y) + bf16_f(r1.y)) + (bf16_f(r2.y) + bf16_f(r3.y));
        a2 += (bf16_f(r0.z) + bf16_f(r1.z)) + (bf16_f(r2.z) + bf16_f(r3.z));
        as += (bf16_f(r0.w) + bf16_f(r1.w)) + (bf16_f(r2.w) + bf16_f(r3.w));
    }
    for (; j < end; j++) {
        ushort4 r = VM[(size_t)src_sorted[j] * FDIM + c];
        a0 += bf16_f(r.x); a1 += bf16_f(r.y); a2 += bf16_f(r.z); as += bf16_f(r.w);
    }

    out_s[(size_t)d * FDIM + c] = node_s[(size_t)d * FDIM + c] + as;
    const float* ip = node_vec + (size_t)d * 384 + 3 * c;
    float* op = out_vec + (size_t)d * 384 + 3 * c;
    op[0] = ip[0] + a0;
    op[1] = ip[1] + a1;
    op[2] = ip[2] + a2;
}

extern "C" void kernel_launch(void* const* d_in, const int* in_sizes, int n_in,
                              void* d_out, int out_size, void* d_ws, size_t ws_size,
                              hipStream_t stream) {
    const float* node_s   = (const float*)d_in[0];
    const float* node_vec = (const float*)d_in[1];
    const int*   edge     = (const int*)d_in[2];
    const float* edge_dis = (const float*)d_in[4];
    const float* W1 = (const float*)d_in[5];
    const float* b1 = (const float*)d_in[6];
    const float* W2 = (const float*)d_in[7];
    const float* b2 = (const float*)d_in[8];
    const float* Wf = (const float*)d_in[9];
    const float* bf = (const float*)d_in[10];

    const int N = in_sizes[0] / FDIM;
    const int E = in_sizes[2] / 2;

    float* out_vec = (float*)d_out;              // N*128*3
    float* out_s   = out_vec + (size_t)N * 384;  // N*128

    // workspace layout (~22 MB)
    int* counts     = (int*)d_ws;          // N
    int* offsets    = counts + N;          // N+1
    int* cursor     = offsets + N + 1;     // N
    int* src_sorted = cursor + N;          // E
    size_t int_bytes = (((size_t)(3 * N + 1 + E) * 4) + 15) & ~(size_t)15;
    unsigned short* W1T = (unsigned short*)((char*)d_ws + int_bytes);  // 128*128
    unsigned short* W2T = W1T + 128 * 128;                             // 256*128
    unsigned short* WfT = W2T + 256 * 128;                             // 256*32
    ushort4*        VMh = (ushort4*)(WfT + 256 * 32);                  // N*128

    hipMemsetAsync(counts, 0, (size_t)N * sizeof(int), stream);

    convert_w<<<(128 * 128 + 256 * 128 + 256 * 32 + 255) / 256, 256, 0, stream>>>(
        W1, W2, Wf, W1T, W2T, WfT);

    node_fused<<<(N + 31) / 32, 256, 0, stream>>>(
        node_s, node_vec, edge_dis, W1T, b1, W2T, b2, WfT, bf, VMh, N);

    hist_kernel<<<(E + 255) / 256, 256, 0, stream>>>(edge, counts, E);
    scan_kernel<<<1, 1024, 0, stream>>>(counts, offsets, cursor, N);
    scatter_kernel<<<(E + 255) / 256, 256, 0, stream>>>(edge, cursor, src_sorted, E);

    gather_bf16<<<(N + 1) / 2, 256, 0, stream>>>(
        offsets, src_sorted, VMh, node_vec, node_s, out_vec, out_s, N);
}

// Round 9
// 246.934 us; speedup vs baseline: 1.4824x; 1.0617x over previous
//
#include <hip/hip_runtime.h>
#include <hip/hip_bf16.h>

#define FDIM 128
#define NRBF 20
#define PI_OVER_CUT 0.6283185307179586f  // pi / 5.0

// weight-conversion element counts (prep_kernel block split)
#define WCONV_ELEMS (128 * 128 + 256 * 128 + 256 * 32)   // 57344
#define WCONV_BLOCKS (WCONV_ELEMS / 256)                 // 224

typedef short bf8_t __attribute__((ext_vector_type(8)));   // 8 bf16 (4 VGPRs)
typedef float f4_t  __attribute__((ext_vector_type(4)));   // 4 fp32 acc

static __device__ __forceinline__ unsigned short bf16_bits(float x) {
    unsigned u = __float_as_uint(x);
    unsigned r = u + 0x7FFF + ((u >> 16) & 1);   // round-to-nearest-even
    return (unsigned short)(r >> 16);
}
static __device__ __forceinline__ float bf16_f(unsigned short b) {
    return __uint_as_float(((unsigned)b) << 16);
}

// ---- prep: weight conversion (blocks [0,224)) + dst histogram (rest) ------
//   W1T[n][k] = W1[k][n]               (128x128)
//   W2T[n][k] = W2[k][colmap(n)]       (256x128), colmap(n)= n<128 ? n : n+128
//   WfT[n][k] = k<20 ? Wf[k][colmap(n)] : 0   (256x32, K padded 20->32)
__global__ __launch_bounds__(256) void prep_kernel(
    const float* __restrict__ W1, const float* __restrict__ W2,
    const float* __restrict__ Wf,
    unsigned short* __restrict__ W1T, unsigned short* __restrict__ W2T,
    unsigned short* __restrict__ WfT,
    const int* __restrict__ edge, int* __restrict__ counts, int E)
{
    int b = blockIdx.x;
    if (b < WCONV_BLOCKS) {
        int i = b * 256 + threadIdx.x;
        if (i < 128 * 128) {
            int n = i >> 7, k = i & 127;
            W1T[n * 128 + k] = bf16_bits(W1[k * 128 + n]);
        } else if (i < 128 * 128 + 256 * 128) {
            int j = i - 128 * 128;
            int n = j >> 7, k = j & 127;
            int col = (n < 128) ? n : n + 128;
            W2T[n * 128 + k] = bf16_bits(W2[k * 384 + col]);
        } else {
            int j = i - (128 * 128 + 256 * 128);
            int n = j >> 5, k = j & 31;
            int col = (n < 128) ? n : n + 128;
            WfT[n * 32 + k] = (k < NRBF) ? bf16_bits(Wf[k * 384 + col])
                                         : (unsigned short)0;
        }
    } else {
        int i = (b - WCONV_BLOCKS) * 256 + threadIdx.x;
        if (i < E) atomicAdd(&counts[edge[2 * i]], 1);
    }
}

// ---- fully fused per-node kernel (16 rows/block, 4 waves = col-quarters) --
__global__ __launch_bounds__(256) void node_fused(
    const float* __restrict__ S, const float* __restrict__ node_vec,
    const float* __restrict__ edge_dis,
    const unsigned short* __restrict__ W1T, const float* __restrict__ b1,
    const unsigned short* __restrict__ W2T, const float* __restrict__ b2,
    const unsigned short* __restrict__ WfT, const float* __restrict__ bfv,
    ushort4* __restrict__ VM, int N)
{
    __shared__ __align__(16) unsigned short sh_s[16][136];
    __shared__ __align__(16) unsigned short sh_h[16][136];
    __shared__ __align__(16) unsigned short sh_rbf[16][40];
    __shared__ float sh_ccut[16];

    const int tid  = threadIdx.x;
    const int lane = tid & 63;
    const int wave = tid >> 6;      // 0..3: column quarter
    const int l15  = lane & 15;
    const int quad = lane >> 4;
    const int m0   = blockIdx.x * 16;

    // ---- phase 0: staging ----
    for (int t = tid; t < 16 * 32; t += 256) {          // node_s: 512 float4
        int row = t >> 5, c4 = (t & 31) * 4;
        int n = m0 + row; if (n >= N) n = N - 1;
        float4 x = *(const float4*)(S + (size_t)n * FDIM + c4);
        ushort4 u;
        u.x = bf16_bits(x.x); u.y = bf16_bits(x.y);
        u.z = bf16_bits(x.z); u.w = bf16_bits(x.w);
        *(ushort4*)&sh_s[row][c4] = u;
    }
    if (tid < 16 * 8) {                                  // rbf: 16 rows x 8 k-quads
        int row = tid >> 3, k0 = (tid & 7) * 4;
        int n = m0 + row; if (n >= N) n = N - 1;
        float dd = edge_dis[n];
        float ph = PI_OVER_CUT * dd;
        float inv = 1.0f / dd;
        ushort4 u;
        u.x = (k0 + 0 < NRBF) ? bf16_bits(sinf((float)(k0 + 1) * ph) * inv) : 0;
        u.y = (k0 + 1 < NRBF) ? bf16_bits(sinf((float)(k0 + 2) * ph) * inv) : 0;
        u.z = (k0 + 2 < NRBF) ? bf16_bits(sinf((float)(k0 + 3) * ph) * inv) : 0;
        u.w = (k0 + 3 < NRBF) ? bf16_bits(sinf((float)(k0 + 4) * ph) * inv) : 0;
        *(ushort4*)&sh_rbf[row][k0] = u;
    }
    if (tid < 16) {
        int n = m0 + tid; if (n >= N) n = N - 1;
        float dd = edge_dis[n];
        sh_ccut[tid] = (dd <= 5.0f) ? 0.5f * (cosf(PI_OVER_CUT * dd) + 1.0f) : 0.0f;
    }
    __syncthreads();

    // ---- phase 1: GEMM1 + silu -> sh_h (wave owns 2 col-tiles) ----
    {
        bf8_t a1[4];
        #pragma unroll
        for (int kk = 0; kk < 4; kk++)
            a1[kk] = *(const bf8_t*)&sh_s[l15][kk * 32 + quad * 8];

        #pragma unroll
        for (int i = 0; i < 2; i++) {
            int col = (wave * 2 + i) * 16 + l15;
            const unsigned short* wp = W1T + (size_t)col * FDIM + quad * 8;
            f4_t acc = {0.f, 0.f, 0.f, 0.f};
            #pragma unroll
            for (int kk = 0; kk < 4; kk++) {
                bf8_t b = *(const bf8_t*)(wp + kk * 32);
                acc = __builtin_amdgcn_mfma_f32_16x16x32_bf16(a1[kk], b, acc, 0, 0, 0);
            }
            float bb = b1[col];
            #pragma unroll
            for (int r = 0; r < 4; r++) {
                float x = acc[r] + bb;
                x = x / (1.f + expf(-x));
                sh_h[quad * 4 + r][col] = bf16_bits(x);
            }
        }
    }
    __syncthreads();

    // ---- phase 2: GEMM2 (gate+msg) + filter GEMM + epilogue ----
    bf8_t a2[4], af;
    #pragma unroll
    for (int kk = 0; kk < 4; kk++)
        a2[kk] = *(const bf8_t*)&sh_h[l15][kk * 32 + quad * 8];
    af = *(const bf8_t*)&sh_rbf[l15][quad * 8];

    #pragma unroll
    for (int i = 0; i < 2; i++) {
        int pc = (wave * 2 + i) * 16 + l15;      // packed col 0..127
        const unsigned short* wg = W2T + (size_t)pc * FDIM + quad * 8;
        const unsigned short* wm = W2T + (size_t)(pc + 128) * FDIM + quad * 8;
        f4_t ag = {0.f, 0.f, 0.f, 0.f}, am = {0.f, 0.f, 0.f, 0.f};
        #pragma unroll
        for (int kk = 0; kk < 4; kk++) {
            bf8_t bg = *(const bf8_t*)(wg + kk * 32);
            bf8_t bm = *(const bf8_t*)(wm + kk * 32);
            ag = __builtin_amdgcn_mfma_f32_16x16x32_bf16(a2[kk], bg, ag, 0, 0, 0);
            am = __builtin_amdgcn_mfma_f32_16x16x32_bf16(a2[kk], bm, am, 0, 0, 0);
        }
        f4_t fg = {0.f, 0.f, 0.f, 0.f}, fm = {0.f, 0.f, 0.f, 0.f};
        {
            bf8_t bg = *(const bf8_t*)(WfT + (size_t)pc * 32 + quad * 8);
            bf8_t bm = *(const bf8_t*)(WfT + (size_t)(pc + 128) * 32 + quad * 8);
            fg = __builtin_amdgcn_mfma_f32_16x16x32_bf16(af, bg, fg, 0, 0, 0);
            fm = __builtin_amdgcn_mfma_f32_16x16x32_bf16(af, bm, fm, 0, 0, 0);
        }

        float b2g = b2[pc], b2m = b2[256 + pc];
        float bfg = bfv[pc], bfm = bfv[256 + pc];
        #pragma unroll
        for (int r = 0; r < 4; r++) {
            int lrow = quad * 4 + r;
            int n = m0 + lrow;
            if (n < N) {
                float cc = sh_ccut[lrow];
                float a  = (fg[r] + bfg) * cc * (ag[r] + b2g);
                float mv = (fm[r] + bfm) * cc * (am[r] + b2m);
                const float* vp = node_vec + (size_t)n * 384 + 3 * pc;
                ushort4 rec;
                rec.x = bf16_bits(a * vp[0]);
                rec.y = bf16_bits(a * vp[1]);
                rec.z = bf16_bits(a * vp[2]);
                rec.w = bf16_bits(mv);
                VM[(size_t)n * FDIM + pc] = rec;
            }
        }
    }
}

// ---- single-block scan, LDS-staged (coalesced global reads) ---------------
__global__ __launch_bounds__(1024) void scan_kernel(
    const int* __restrict__ counts, int* __restrict__ offsets,
    int* __restrict__ cursor, int N)
{
    __shared__ unsigned short lds_cnt[20000];   // counts fit in 16 bits (deg ~16)
    __shared__ int sh[1024];
    const int t = threadIdx.x;
    const int chunk = (N + 1023) / 1024;
    const int beg = t * chunk, end = min(beg + chunk, N);

    for (int i = t; i < N; i += 1024) lds_cnt[i] = (unsigned short)counts[i];
    __syncthreads();

    int local = 0;
    for (int i = beg; i < end; i++) local += lds_cnt[i];
    sh[t] = local;
    __syncthreads();
    for (int off = 1; off < 1024; off <<= 1) {
        int v = (t >= off) ? sh[t - off] : 0;
        __syncthreads();
        sh[t] += v;
        __syncthreads();
    }
    int run = sh[t] - local;  // exclusive prefix of this chunk
    for (int i = beg; i < end; i++) {
        offsets[i] = run;
        cursor[i] = run;
        run += lds_cnt[i];
    }
    if (t == 1023) offsets[N] = sh[1023];
}

__global__ __launch_bounds__(256) void scatter_kernel(
    const int* __restrict__ edge, int* __restrict__ cursor,
    int* __restrict__ src_sorted, int E)
{
    int i = blockIdx.x * 256 + threadIdx.x;
    if (i >= E) return;
    int d = edge[2 * i];
    int s = edge[2 * i + 1];
    int pos = atomicAdd(&cursor[d], 1);
    src_sorted[pos] = s;
}

// ------- gather: one dst per 128 threads, 8B bf16 records, 8x unroll -------
__global__ __launch_bounds__(256) void gather_bf16(
    const int* __restrict__ offsets, const int* __restrict__ src_sorted,
    const ushort4* __restrict__ VM, const float* __restrict__ node_vec,
    const float* __restrict__ node_s,
    float* __restrict__ out_vec, float* __restrict__ out_s, int N)
{
    int d = blockIdx.x * 2 + (threadIdx.x >> 7);
    int c = threadIdx.x & 127;
    if (d >= N) return;

    int beg = offsets[d];
    int end = offsets[d + 1];

    float a0 = 0.f, a1 = 0.f, a2 = 0.f, as = 0.f;
    int j = beg;
    for (; j + 7 < end; j += 8) {
        ushort4 r0 = VM[(size_t)src_sorted[j]     * FDIM + c];
        ushort4 r1 = VM[(size_t)src_sorted[j + 1] * FDIM + c];
        ushort4 r2 = VM[(size_t)src_sorted[j + 2] * FDIM + c];
        ushort4 r3 = VM[(size_t)src_sorted[j + 3] * FDIM + c];
        ushort4 r4 = VM[(size_t)src_sorted[j + 4] * FDIM + c];
        ushort4 r5 = VM[(size_t)src_sorted[j + 5] * FDIM + c];
        ushort4 r6 = VM[(size_t)src_sorted[j + 6] * FDIM + c];
        ushort4 r7 = VM[(size_t)src_sorted[j + 7] * FDIM + c];
        a0 += ((bf16_f(r0.x) + bf16_f(r1.x)) + (bf16_f(r2.x) + bf16_f(r3.x)))
            + ((bf16_f(r4.x) + bf16_f(r5.x)) + (bf16_f(r6.x) + bf16_f(r7.x)));
        a1 += ((bf16_f(r0.y) + bf16_f(r1.y)) + (bf16_f(r2.y) + bf16_f(r3.y)))
            + ((bf16_f(r4.y) + bf16_f(r5.y)) + (bf16_f(r6.y) + bf16_f(r7.y)));
        a2 += ((bf16_f(r0.z) + bf16_f(r1.z)) + (bf16_f(r2.z) + bf16_f(r3.z)))
            + ((bf16_f(r4.z) + bf16_f(r5.z)) + (bf16_f(r6.z) + bf16_f(r7.z)));
        as += ((bf16_f(r0.w) + bf16_f(r1.w)) + (bf16_f(r2.w) + bf16_f(r3.w)))
            + ((bf16_f(r4.w) + bf16_f(r5.w)) + (bf16_f(r6.w) + bf16_f(r7.w)));
    }
    for (; j + 3 < end; j += 4) {
        ushort4 r0 = VM[(size_t)src_sorted[j]     * FDIM + c];
        ushort4 r1 = VM[(size_t)src_sorted[j + 1] * FDIM + c];
        ushort4 r2 = VM[(size_t)src_sorted[j + 2] * FDIM + c];
        ushort4 r3 = VM[(size_t)src_sorted[j + 3] * FDIM + c];
        a0 += (bf16_f(r0.x) + bf16_f(r1.x)) + (bf16_f(r2.x) + bf16_f(r3.x));
        a1 += (bf16_f(r0.y) + bf16_f(r1.y)) + (bf16_f(r2.y) + bf16_f(r3.y));
        a2 += (bf16_f(r0.z) + bf16_f(r1.z)) + (bf16_f(r2.z) + bf16_f(r3.z));
        as += (bf16_f(r0.w) + bf16_f(r1.w)) + (bf16_f(r2.w) + bf16_f(r3.w));
    }
    for (; j < end; j++) {
        ushort4 r = VM[(size_t)src_sorted[j] * FDIM + c];
        a0 += bf16_f(r.x); a1 += bf16_f(r.y); a2 += bf16_f(r.z); as += bf16_f(r.w);
    }

    out_s[(size_t)d * FDIM + c] = node_s[(size_t)d * FDIM + c] + as;
    const float* ip = node_vec + (size_t)d * 384 + 3 * c;
    float* op = out_vec + (size_t)d * 384 + 3 * c;
    op[0] = ip[0] + a0;
    op[1] = ip[1] + a1;
    op[2] = ip[2] + a2;
}

extern "C" void kernel_launch(void* const* d_in, const int* in_sizes, int n_in,
                              void* d_out, int out_size, void* d_ws, size_t ws_size,
                              hipStream_t stream) {
    const float* node_s   = (const float*)d_in[0];
    const float* node_vec = (const float*)d_in[1];
    const int*   edge     = (const int*)d_in[2];
    const float* edge_dis = (const float*)d_in[4];
    const float* W1 = (const float*)d_in[5];
    const float* b1 = (const float*)d_in[6];
    const float* W2 = (const float*)d_in[7];
    const float* b2 = (const float*)d_in[8];
    const float* Wf = (const float*)d_in[9];
    const float* bf = (const float*)d_in[10];

    const int N = in_sizes[0] / FDIM;
    const int E = in_sizes[2] / 2;

    float* out_vec = (float*)d_out;              // N*128*3
    float* out_s   = out_vec + (size_t)N * 384;  // N*128

    // workspace layout (~22 MB)
    int* counts     = (int*)d_ws;          // N
    int* offsets    = counts + N;          // N+1
    int* cursor     = offsets + N + 1;     // N
    int* src_sorted = cursor + N;          // E
    size_t int_bytes = (((size_t)(3 * N + 1 + E) * 4) + 15) & ~(size_t)15;
    unsigned short* W1T = (unsigned short*)((char*)d_ws + int_bytes);  // 128*128
    unsigned short* W2T = W1T + 128 * 128;                             // 256*128
    unsigned short* WfT = W2T + 256 * 128;                             // 256*32
    ushort4*        VMh = (ushort4*)(WfT + 256 * 32);                  // N*128

    hipMemsetAsync(counts, 0, (size_t)N * sizeof(int), stream);

    const int hist_blocks = (E + 255) / 256;
    prep_kernel<<<WCONV_BLOCKS + hist_blocks, 256, 0, stream>>>(
        W1, W2, Wf, W1T, W2T, WfT, edge, counts, E);

    node_fused<<<(N + 15) / 16, 256, 0, stream>>>(
        node_s, node_vec, edge_dis, W1T, b1, W2T, b2, WfT, bf, VMh, N);

    scan_kernel<<<1, 1024, 0, stream>>>(counts, offsets, cursor, N);
    scatter_kernel<<<(E + 255) / 256, 256, 0, stream>>>(edge, cursor, src_sorted, E);

    gather_bf16<<<(N + 1) / 2, 256, 0, stream>>>(
        offsets, src_sorted, VMh, node_vec, node_s, out_vec, out_s, N);
}